// Round 3
// baseline (240.569 us; speedup 1.0000x reference)
//
#include <hip/hip_runtime.h>

// Problem constants (fixed by setup_inputs): B=32, C=256, H=W=64
#define BATCH 32
#define CHAN  256
#define HGT   64
#define WID   64
#define HW    4096            // HGT*WID
#define CPB   8               // channels per block
#define NBLK  (BATCH * (CHAN / CPB))   // 1024 blocks

// Fused: each block (b, g) builds the per-batch bilinear scatter-weight map
// A[b] in LDS (redundantly per channel-group; offset reads are L2-shared),
// then computes out[b, g*8 .. g*8+7] = dot(A, data[b,c,:]) / 4096 by
// streaming 8 channel planes with channel-interleaved float4 loads.
__global__ __launch_bounds__(256) void fused_bilinear_pool_kernel(
        const float* __restrict__ data,     // [B, C, H, W] fp32
        const float* __restrict__ offset,   // [B, 2, H, W] fp32
        const float* __restrict__ ts_ptr,   // scalar fp32
        float* __restrict__ out)            // [B, C] fp32
{
    const int tid = threadIdx.x;
    const int b   = blockIdx.x >> 5;        // batch
    const int g   = blockIdx.x & 31;        // channel group (8 channels)

    __shared__ float A[HW];                 // 16 KiB weight map
    __shared__ float red[4 * CPB];          // cross-wave reduction scratch

    for (int k = tid; k < HW; k += 256) A[k] = 0.0f;
    __syncthreads();

    float ts = ts_ptr[0];
    ts = fminf(fmaxf(ts, 0.001f), 0.01f);

    const float* off_y = offset + (size_t)b * 2 * HW;   // offset[b,0]
    const float* off_x = off_y + HW;                    // offset[b,1]

    // Phase 1: scatter-accumulate bilinear weights into A (LDS atomics).
    // 4096 pixels / 256 threads = 16 pixels/thread as 4 iters x float4.
    #pragma unroll
    for (int it = 0; it < 4; ++it) {
        const int p4 = (it * 256 + tid) * 4;            // 4 consecutive pixels
        const float4 dy4 = *reinterpret_cast<const float4*>(off_y + p4);
        const float4 dx4 = *reinterpret_cast<const float4*>(off_x + p4);
        const float dys[4] = {dy4.x, dy4.y, dy4.z, dy4.w};
        const float dxs[4] = {dx4.x, dx4.y, dx4.z, dx4.w};
        #pragma unroll
        for (int u = 0; u < 4; ++u) {
            const int p = p4 + u;
            const int i = p >> 6;
            const int j = p & 63;
            // reference: y = clip(i + (ts*offset)*H, 0, H-1)
            float y = fminf(fmaxf((float)i + ts * dys[u] * 64.0f, 0.0f), 63.0f);
            float x = fminf(fmaxf((float)j + ts * dxs[u] * 64.0f, 0.0f), 63.0f);
            int y0 = (int)floorf(y); y0 = min(max(y0, 0), HGT - 2);
            int x0 = (int)floorf(x); x0 = min(max(x0, 0), WID - 2);
            const float wy = y - (float)y0;
            const float wx = x - (float)x0;
            const int base = (y0 << 6) + x0;
            atomicAdd(&A[base],           (1.0f - wy) * (1.0f - wx));
            atomicAdd(&A[base + 1],       (1.0f - wy) * wx);
            atomicAdd(&A[base + WID],     wy * (1.0f - wx));
            atomicAdd(&A[base + WID + 1], wy * wx);
        }
    }
    __syncthreads();

    // Phase 2: stream 8 channel planes, dot against A (LDS).
    const float* planes = data + ((size_t)b * CHAN + (size_t)g * CPB) * HW;

    float sums[CPB];
    #pragma unroll
    for (int c = 0; c < CPB; ++c) sums[c] = 0.0f;

    #pragma unroll
    for (int it = 0; it < 4; ++it) {
        const int idx = (it * 256 + tid) * 4;           // 4 fp32 / thread / iter
        const float4 av = *reinterpret_cast<const float4*>(&A[idx]);   // ds_read_b128
        #pragma unroll
        for (int c = 0; c < CPB; ++c) {
            const float4 dv = *reinterpret_cast<const float4*>(planes + (size_t)c * HW + idx);
            sums[c] = fmaf(av.x, dv.x, sums[c]);
            sums[c] = fmaf(av.y, dv.y, sums[c]);
            sums[c] = fmaf(av.z, dv.z, sums[c]);
            sums[c] = fmaf(av.w, dv.w, sums[c]);
        }
    }

    // Per-channel wave-64 shuffle reduce, then cross-wave via LDS.
    #pragma unroll
    for (int c = 0; c < CPB; ++c) {
        float s = sums[c];
        #pragma unroll
        for (int off = 32; off > 0; off >>= 1)
            s += __shfl_down(s, off, 64);
        sums[c] = s;
    }
    const int lane = tid & 63;
    const int wv   = tid >> 6;
    if (lane == 0) {
        #pragma unroll
        for (int c = 0; c < CPB; ++c) red[wv * CPB + c] = sums[c];
    }
    __syncthreads();
    if (tid < CPB) {
        const float t = red[0 * CPB + tid] + red[1 * CPB + tid] +
                        red[2 * CPB + tid] + red[3 * CPB + tid];
        out[(size_t)b * CHAN + g * CPB + tid] = t * (1.0f / (float)HW);
    }
}

extern "C" void kernel_launch(void* const* d_in, const int* in_sizes, int n_in,
                              void* d_out, int out_size, void* d_ws, size_t ws_size,
                              hipStream_t stream) {
    const float* data   = (const float*)d_in[0];  // fp32 [32,256,64,64]
    const float* offset = (const float*)d_in[1];  // fp32 [32,2,64,64]
    const float* ts     = (const float*)d_in[2];  // fp32 scalar
    float* out = (float*)d_out;                   // [32, 256] fp32

    fused_bilinear_pool_kernel<<<NBLK, 256, 0, stream>>>(data, offset, ts, out);
}

// Round 5
// 212.970 us; speedup vs baseline: 1.1296x; 1.1296x over previous
//
#include <hip/hip_runtime.h>

// Problem constants (fixed by setup_inputs): B=32, C=256, H=W=64
#define BATCH 32
#define CHAN  256
#define HGT   64
#define WID   64
#define HW    4096   // HGT*WID

// Kernel 1: per-batch scatter-accumulated bilinear weight map A[b, 0:4096].
// One block per batch; LDS float atomicAdd. Mean (1/4096) folded in.
__global__ __launch_bounds__(256) void weight_map_kernel(
        const float* __restrict__ offset,   // [B, 2, H, W] fp32
        const float* __restrict__ ts_ptr,   // scalar fp32
        float* __restrict__ A)              // [B, 4096] fp32 (d_ws)
{
    const int b   = blockIdx.x;
    const int tid = threadIdx.x;

    __shared__ float acc[HW];   // 16 KiB
    for (int k = tid; k < HW; k += 256) acc[k] = 0.0f;
    __syncthreads();

    float ts = ts_ptr[0];
    ts = fminf(fmaxf(ts, 0.001f), 0.01f);

    const float* off_y = offset + (size_t)b * 2 * HW;   // offset[b,0]
    const float* off_x = off_y + HW;                    // offset[b,1]

    for (int p = tid; p < HW; p += 256) {
        const int i = p >> 6;
        const int j = p & 63;
        const float dy = off_y[p];
        const float dx = off_x[p];
        float y = fminf(fmaxf((float)i + ts * dy * 64.0f, 0.0f), 63.0f);
        float x = fminf(fmaxf((float)j + ts * dx * 64.0f, 0.0f), 63.0f);
        int y0 = (int)floorf(y); y0 = min(max(y0, 0), HGT - 2);
        int x0 = (int)floorf(x); x0 = min(max(x0, 0), WID - 2);
        const float wy = y - (float)y0;
        const float wx = x - (float)x0;
        const int base = (y0 << 6) + x0;
        atomicAdd(&acc[base],           (1.0f - wy) * (1.0f - wx));
        atomicAdd(&acc[base + 1],       (1.0f - wy) * wx);
        atomicAdd(&acc[base + WID],     wy * (1.0f - wx));
        atomicAdd(&acc[base + WID + 1], wy * wx);
    }
    __syncthreads();

    float* Ab = A + (size_t)b * HW;
    const float s = 1.0f / (float)HW;
    for (int k = tid; k < HW; k += 256) Ab[k] = acc[k] * s;
}

// Kernel 2: one WAVE per (b,c) plane; no LDS, no barriers, no atomics.
// FULL coverage: 16 float4 data loads + 16 float4 A loads per lane
// (4096 floats / 64 lanes = 64 floats/lane), looped 4x(4+4) so ~32 payload
// VGPRs stay live -> 8 waves/SIMD; 8192 waves fill all 8192 wave slots.
__global__ __launch_bounds__(256) void dot_kernel(
        const float* __restrict__ data,   // [B, C, H, W] fp32
        const float* __restrict__ A,      // [B, 4096] fp32
        float* __restrict__ out)          // [B, C] fp32
{
    const int wave = (blockIdx.x << 2) | (threadIdx.x >> 6);  // plane id = b*256+c
    const int lane = threadIdx.x & 63;
    const int b    = wave >> 8;

    const float* plane = data + (size_t)wave * HW;
    const float* Ab    = A    + (size_t)b    * HW;
    const int o = lane << 2;            // lane*4 floats

    float s0 = 0.0f, s1 = 0.0f, s2 = 0.0f, s3 = 0.0f;

    #pragma unroll
    for (int it = 0; it < 4; ++it) {
        const int base = it * 1024 + o;   // 4 chunks of 256 floats per iter
        const float4 d0 = *reinterpret_cast<const float4*>(plane + base);
        const float4 d1 = *reinterpret_cast<const float4*>(plane + base + 256);
        const float4 d2 = *reinterpret_cast<const float4*>(plane + base + 512);
        const float4 d3 = *reinterpret_cast<const float4*>(plane + base + 768);
        const float4 a0 = *reinterpret_cast<const float4*>(Ab + base);
        const float4 a1 = *reinterpret_cast<const float4*>(Ab + base + 256);
        const float4 a2 = *reinterpret_cast<const float4*>(Ab + base + 512);
        const float4 a3 = *reinterpret_cast<const float4*>(Ab + base + 768);
        s0 = fmaf(a0.x, d0.x, s0); s0 = fmaf(a0.y, d0.y, s0);
        s0 = fmaf(a0.z, d0.z, s0); s0 = fmaf(a0.w, d0.w, s0);
        s1 = fmaf(a1.x, d1.x, s1); s1 = fmaf(a1.y, d1.y, s1);
        s1 = fmaf(a1.z, d1.z, s1); s1 = fmaf(a1.w, d1.w, s1);
        s2 = fmaf(a2.x, d2.x, s2); s2 = fmaf(a2.y, d2.y, s2);
        s2 = fmaf(a2.z, d2.z, s2); s2 = fmaf(a2.w, d2.w, s2);
        s3 = fmaf(a3.x, d3.x, s3); s3 = fmaf(a3.y, d3.y, s3);
        s3 = fmaf(a3.z, d3.z, s3); s3 = fmaf(a3.w, d3.w, s3);
    }

    float s = (s0 + s1) + (s2 + s3);

    #pragma unroll
    for (int off = 32; off > 0; off >>= 1)
        s += __shfl_down(s, off, 64);

    if (lane == 0) out[wave] = s;
}

extern "C" void kernel_launch(void* const* d_in, const int* in_sizes, int n_in,
                              void* d_out, int out_size, void* d_ws, size_t ws_size,
                              hipStream_t stream) {
    const float* data   = (const float*)d_in[0];  // fp32 [32,256,64,64]
    const float* offset = (const float*)d_in[1];  // fp32 [32,2,64,64]
    const float* ts     = (const float*)d_in[2];  // fp32 scalar

    float* A   = (float*)d_ws;   // [32, 4096] fp32 = 512 KiB scratch
    float* out = (float*)d_out;  // [32, 256] fp32

    weight_map_kernel<<<BATCH, 256, 0, stream>>>(offset, ts, A);
    dot_kernel<<<(BATCH * CHAN) / 4, 256, 0, stream>>>(data, A, out);
}